// Round 4
// baseline (209.870 us; speedup 1.0000x reference)
//
#include <hip/hip_runtime.h>
#include <hip/hip_bf16.h>

typedef __attribute__((ext_vector_type(8))) __bf16 bf16x8;
typedef __attribute__((ext_vector_type(4))) float f32x4;

#define S_TOK 4096
#define NB 2
#define NH 16
#define DH 128
#define DEG 4
#define SSP 1024
#define QB 64
#define KB 64
#define TOKS (NB * NH * DH) /* 4096 floats per token */
#define SCALE 0.08838834764831845f
#define VP 148              /* V^T row pitch bytes (37 words): <=2-way banks */
#define KSZ (KB * 256)      /* 16384 */
#define VSZ (64 * VP)       /* 9472  */
#define BUFSZ (KSZ + VSZ)   /* 25856 */

union U8 {
  bf16x8 v;
  unsigned u[4];
  unsigned short s[8];
};

__device__ __forceinline__ unsigned short f2bfu(float x) {
  __bf16 b = (__bf16)x;  // RNE; pairs into v_cvt_pk_bf16_f32
  return __builtin_bit_cast(unsigned short, b);
}
__device__ __forceinline__ unsigned pkbf(float lo, float hi) {
  return (unsigned)f2bfu(lo) | ((unsigned)f2bfu(hi) << 16);
}

// Block = (bh, pair j, d-half). Processes q-tiles {j, 15-j} sequentially:
// every block does exactly 17 tile-steps -> zero load-imbalance tail.
// LDS: 2 x { K[64][128] bf16 XOR-swizzled (16KB) + V^T[64 d][64 s] pitch-148 }.
__global__ __launch_bounds__(256, 2) void mlsa_fused(
    const float* __restrict__ Qg, const float* __restrict__ Kg,
    const float* __restrict__ Vg, float* __restrict__ Og,
    float* __restrict__ Dg) {
  __shared__ __align__(16) char lds[2 * BUFSZ];

  const int bid = blockIdx.x;
  const int bh = bid & 31;
  const int j = (bid >> 5) & 7;
  const int dhv = bid >> 8;  // d-half: 0 or 1
  const int b = bh >> 4;
  const int h = bh & 15;
  const int hm4 = h & 3;
  const int tid = (int)threadIdx.x;
  const int wv = tid >> 6;
  const int ln = tid & 63;
  const int g = ln >> 4;
  const int c = ln & 15;
  const size_t bhoff = (size_t)b * (NH * DH) + (size_t)h * DH;
  const int dbase = dhv * 64;

  const int krow = tid >> 2;      // K-stage row 0..63
  const int kd0 = (tid & 3) * 8;  // 4 lanes per 128-float K row
  const int vd4 = tid & 15;       // V-stage (d-half)/4: 0..15
  const int vsp = tid >> 4;       // 0..15 -> s = pp*32 + vsp*2

  f32x4 kreg[8], vreg[4];
  auto issue_kv = [&](int kt) {
    const float* kr =
        Kg + (size_t)((kt * KB + krow) * DEG + hm4) * TOKS + bhoff + kd0;
    #pragma unroll
    for (int p4 = 0; p4 < 4; ++p4) {
      kreg[2 * p4] = *(const f32x4*)(kr + p4 * 32);
      kreg[2 * p4 + 1] = *(const f32x4*)(kr + p4 * 32 + 4);
    }
    #pragma unroll
    for (int pp = 0; pp < 2; ++pp) {
      int s = kt * KB + pp * 32 + vsp * 2;
      const float* vr =
          Vg + (size_t)(s * DEG + hm4) * TOKS + bhoff + dbase + vd4 * 4;
      vreg[2 * pp] = *(const f32x4*)vr;
      vreg[2 * pp + 1] = *(const f32x4*)(vr + (size_t)DEG * TOKS);
    }
  };

  U8 kpk[4];
  unsigned vpk[2][4];
  auto conv = [&]() {
    #pragma unroll
    for (int p4 = 0; p4 < 4; ++p4) {
      #pragma unroll
      for (int i = 0; i < 4; ++i) {
        kpk[p4].s[i] = f2bfu(kreg[2 * p4][i]);
        kpk[p4].s[4 + i] = f2bfu(kreg[2 * p4 + 1][i]);
      }
    }
    #pragma unroll
    for (int pp = 0; pp < 2; ++pp) {
      #pragma unroll
      for (int jj = 0; jj < 4; ++jj)
        vpk[pp][jj] = pkbf(vreg[2 * pp][jj], vreg[2 * pp + 1][jj]);
    }
  };
  auto wr = [&](int buf) {
    char* KL = lds + buf * BUFSZ;
    char* VT = KL + KSZ;
    #pragma unroll
    for (int p4 = 0; p4 < 4; ++p4) {
      int d = kd0 + p4 * 32;
      int byte = (krow * 256 + d * 2) ^ ((krow & 7) << 4);
      *(bf16x8*)(KL + byte) = kpk[p4].v;
    }
    #pragma unroll
    for (int pp = 0; pp < 2; ++pp) {
      int s2 = (pp * 32 + vsp * 2) * 2;
      #pragma unroll
      for (int jj = 0; jj < 4; ++jj)
        *(unsigned*)(VT + (vd4 * 4 + jj) * VP + s2) = vpk[pp][jj];
    }
  };

  int cur = 0;

  for (int ph = 0; ph < 2; ++ph) {
    const int qt = ph ? (15 - j) : j;
    const int qbase = qt * QB + wv * 16;
    const int q_sp = qbase + c;

    // ---- Q loads for this phase ----
    f32x4 qraw[8];
    {
      const float* qrow =
          Qg + (size_t)(q_sp * DEG + hm4) * TOKS + bhoff + g * 8;
      #pragma unroll
      for (int dc = 0; dc < 4; ++dc) {
        qraw[2 * dc] = *(const f32x4*)(qrow + dc * 32);
        qraw[2 * dc + 1] = *(const f32x4*)(qrow + dc * 32 + 4);
      }
    }

    if (ph == 0) {
      issue_kv(0);
      // ---- zero-fill non-selected token offsets for both tiles, this d-half
      const f32x4 z = {0.f, 0.f, 0.f, 0.f};
      for (int u = 0; u < 24; ++u) {
        int fid = u * 256 + tid;
        int col = fid & 15;
        int row = fid >> 4;  // 0..383
        int t2 = row >= 192;
        int r2 = row - (t2 ? 192 : 0);
        int rr = r2 >> 6;
        int qi = (t2 ? (15 - j) : j) * QB + (r2 & 63);
        int off = (hm4 + 1 + rr) & 3;
        *(f32x4*)(Og + (size_t)(qi * DEG + off) * TOKS + bhoff + dbase +
                  col * 4) = z;
      }
    }

    // ---- convert Q (pre-scaled), B-operand layout ----
    bf16x8 qf[4];
    #pragma unroll
    for (int dc = 0; dc < 4; ++dc) {
      U8 t;
      #pragma unroll
      for (int i = 0; i < 4; ++i) {
        t.s[i] = f2bfu(qraw[2 * dc][i] * SCALE);
        t.s[4 + i] = f2bfu(qraw[2 * dc + 1][i] * SCALE);
      }
      qf[dc] = t.v;
    }

    if (ph == 0) {
      conv();
      wr(0);
      __syncthreads();
      cur = 0;
    }

    float m_run = -1e30f, m_true = -1e30f, l_run = 0.f;
    f32x4 acc[4];
    #pragma unroll
    for (int i = 0; i < 4; ++i) acc[i] = (f32x4){0.f, 0.f, 0.f, 0.f};

    for (int kt = 0; kt <= qt; ++kt) {
      const bool diag = (kt == qt);
      const bool has_next = (kt < qt) || (ph == 0);
      if (has_next) {
        issue_kv(diag ? 0 : kt + 1);  // phase crossing prefetches (ph1, kt=0)
        __builtin_amdgcn_sched_barrier(0);
      }

      const char* KL = lds + cur * BUFSZ;
      const char* VT = KL + KSZ;

      // ---- QK^T swapped: C[k_local][q] = K . Q ----
      const int cbmax = diag ? wv : 3;
      f32x4 sc[4];
      #pragma unroll
      for (int cb = 0; cb < 4; ++cb) sc[cb] = (f32x4){0.f, 0.f, 0.f, 0.f};
      #pragma unroll
      for (int cb = 0; cb < 4; ++cb) {
        if (cb <= cbmax) {
          int rbase = (cb * 16 + c) * 256;
          int sw = (c & 7) << 4;
          #pragma unroll
          for (int dc = 0; dc < 4; ++dc) {
            int byte = (rbase + (dc * 32 + g * 8) * 2) ^ sw;
            bf16x8 kf = *(const bf16x8*)(KL + byte);
            sc[cb] =
                __builtin_amdgcn_mfma_f32_16x16x32_bf16(kf, qf[dc], sc[cb], 0, 0, 0);
          }
        }
      }

      // ---- mask + online softmax (lane owns q-column c) ----
      float p[4][4];
      float mt = -1e30f;
      if (!diag) {
        #pragma unroll
        for (int cb = 0; cb < 4; ++cb) {
          #pragma unroll
          for (int r = 0; r < 4; ++r) {
            float v = sc[cb][r];
            p[cb][r] = v;
            mt = fmaxf(mt, v);
          }
        }
      } else {
        const int qloc = wv * 16 + c;
        #pragma unroll
        for (int cb = 0; cb < 4; ++cb) {
          #pragma unroll
          for (int r = 0; r < 4; ++r) {
            int kloc = cb * 16 + g * 4 + r;
            float v = (cb <= cbmax && kloc <= qloc) ? sc[cb][r] : -1e30f;
            p[cb][r] = v;
            mt = fmaxf(mt, v);
          }
        }
      }
      mt = fmaxf(mt, __shfl_xor(mt, 16));
      mt = fmaxf(mt, __shfl_xor(mt, 32));
      m_true = fmaxf(m_true, mt);

      float resc = 1.0f;
      if (!__all(mt <= m_run + 8.0f)) {  // T13 defer-max
        float m_new = fmaxf(m_run, mt);
        resc = __expf(m_run - m_new);
        m_run = m_new;
        #pragma unroll
        for (int r = 0; r < 4; ++r) {
          float f = __shfl(resc, g * 4 + r);
          #pragma unroll
          for (int db = 0; db < 4; ++db) acc[db][r] *= f;
        }
      }
      float ls = 0.f;
      #pragma unroll
      for (int cb = 0; cb < 4; ++cb) {
        #pragma unroll
        for (int r = 0; r < 4; ++r) {
          float e = __expf(p[cb][r] - m_run);
          p[cb][r] = e;
          ls += e;
        }
      }
      ls += __shfl_xor(ls, 16);
      ls += __shfl_xor(ls, 32);
      l_run = l_run * resc + ls;

      // ---- redistribute P into A-operand fragments ----
      unsigned pk2[4][2];
      #pragma unroll
      for (int cb = 0; cb < 4; ++cb) {
        pk2[cb][0] = pkbf(p[cb][0], p[cb][1]);
        pk2[cb][1] = pkbf(p[cb][2], p[cb][3]);
      }
      const int srcA = c + 16 * ((2 * g) & 3);
      const int srcB = c + 16 * ((2 * g + 1) & 3);
      const bool hi = (g & 2) != 0;

      if (has_next) conv();  // vmcnt wait lands here (latency already hidden)

      const int sbmax = diag ? (wv >> 1) : 1;
      #pragma unroll
      for (int sb = 0; sb < 2; ++sb) {
        if (sb <= sbmax) {
          unsigned a0 = (unsigned)__shfl((int)pk2[2 * sb][0], srcA);
          unsigned b0 = (unsigned)__shfl((int)pk2[2 * sb + 1][0], srcA);
          unsigned a1 = (unsigned)__shfl((int)pk2[2 * sb][1], srcA);
          unsigned b1 = (unsigned)__shfl((int)pk2[2 * sb + 1][1], srcA);
          unsigned a2 = (unsigned)__shfl((int)pk2[2 * sb][0], srcB);
          unsigned b2 = (unsigned)__shfl((int)pk2[2 * sb + 1][0], srcB);
          unsigned a3 = (unsigned)__shfl((int)pk2[2 * sb][1], srcB);
          unsigned b3 = (unsigned)__shfl((int)pk2[2 * sb + 1][1], srcB);
          U8 pa;
          pa.u[0] = hi ? b0 : a0;
          pa.u[1] = hi ? b1 : a1;
          pa.u[2] = hi ? b2 : a2;
          pa.u[3] = hi ? b3 : a3;
          #pragma unroll
          for (int db = 0; db < 4; ++db) {
            int byte = (db * 16 + c) * VP + (sb * 32 + g * 8) * 2;
            U8 vb;
            vb.u[0] = *(const unsigned*)(VT + byte);
            vb.u[1] = *(const unsigned*)(VT + byte + 4);
            vb.u[2] = *(const unsigned*)(VT + byte + 8);
            vb.u[3] = *(const unsigned*)(VT + byte + 12);
            acc[db] =
                __builtin_amdgcn_mfma_f32_16x16x32_bf16(pa.v, vb.v, acc[db], 0, 0, 0);
          }
        }
      }

      if (has_next) {
        wr(cur ^ 1);      // stage next tile into the other buffer
        __syncthreads();  // single barrier per tile-step
      }
      cur ^= 1;
    }

    // ---- epilogue: normalize, scatter ctx (this d-half), write denom ----
    float inv = 1.0f / l_run;
    #pragma unroll
    for (int r = 0; r < 4; ++r) {
      float fi = __shfl(inv, g * 4 + r);
      int q2 = qbase + g * 4 + r;
      float* orow = Og + (size_t)(q2 * DEG + hm4) * TOKS + bhoff + dbase;
      #pragma unroll
      for (int db = 0; db < 4; ++db) orow[db * 16 + c] = acc[db][r] * fi;
    }
    if (g == 0 && dhv == 0)
      Dg[(size_t)(qbase + c) * (NB * NH) + b * NH + h] =
          l_run * __expf(m_run - m_true);
  }
}

extern "C" void kernel_launch(void* const* d_in, const int* in_sizes, int n_in,
                              void* d_out, int out_size, void* d_ws, size_t ws_size,
                              hipStream_t stream) {
  (void)in_sizes; (void)n_in; (void)out_size; (void)d_ws; (void)ws_size;
  const float* q = (const float*)d_in[0];
  const float* k = (const float*)d_in[1];
  const float* v = (const float*)d_in[2];
  float* out = (float*)d_out;
  float* den = out + (size_t)S_TOK * NB * NH * DH;
  mlsa_fused<<<dim3(512), dim3(256), 0, stream>>>(q, k, v, out, den);
}